// Round 6
// baseline (53956.305 us; speedup 1.0000x reference)
//
#include <hip/hip_runtime.h>

#define T_STEPS 512
#define BATCH   64
#define IN_SZ   32
#define AD      32
#define INNER   256
#define PROJ    224
#define HID     512
#define SENTW   0x7F7F7F7Fu   // bf16 0x7F7F = 3.3e38; impossible for |h|<1 outputs
#define DEP     16            // ring depth (slots per batch-group)
#define SLOTW   4096          // u32 words per 16KB slot
#define LOC_TO  20000         // local-poll iterations before permanent agent fallback

typedef __attribute__((ext_vector_type(8))) short short8;
typedef __attribute__((ext_vector_type(4))) float f32x4;
typedef __attribute__((ext_vector_type(4))) int   i32x4;

static __device__ __forceinline__ unsigned short f2bf(float f) {
  unsigned int u = __float_as_uint(f);
  u += 0x7FFFu + ((u >> 16) & 1u);
  return (unsigned short)(u >> 16);
}
static __device__ __forceinline__ float sigmoidf_(float x) { return 1.f / (1.f + __expf(-x)); }
static __device__ __forceinline__ float tanhf_(float x) {
  float e = __expf(-2.f * fabsf(x));
  float r = (1.f - e) / (1.f + e);
  return x < 0.f ? -r : r;
}

// ---------------- kernel A: x = [relu(in_w@state+in_b) | emb[idx]] bf16, [t][b][256]
__global__ __launch_bounds__(256) void k_prep(
    const float* __restrict__ ws_in, const int* __restrict__ act_idx,
    const float* __restrict__ emb, const float* __restrict__ in_w,
    const float* __restrict__ in_b, unsigned short* __restrict__ x_bf)
{
  int t = blockIdx.x;
  int tid = threadIdx.x;
  __shared__ float st[BATCH * IN_SZ];
  __shared__ int ai[BATCH];
  for (int i = tid; i < BATCH * IN_SZ; i += 256) {
    int b = i >> 5, k = i & 31;
    st[i] = ws_in[((size_t)b * T_STEPS + t) * IN_SZ + k];
  }
  if (tid < BATCH) ai[tid] = act_idx[tid * T_STEPS + t];
  __syncthreads();
  if (tid < PROJ) {
    float w[IN_SZ];
    const float* wrow = in_w + tid * IN_SZ;
#pragma unroll
    for (int k = 0; k < IN_SZ; ++k) w[k] = wrow[k];
    float bb = in_b[tid];
    for (int b = 0; b < BATCH; ++b) {
      float acc = bb;
      const float* sb = st + b * IN_SZ;
#pragma unroll
      for (int k = 0; k < IN_SZ; ++k) acc += w[k] * sb[k];
      x_bf[((size_t)t * BATCH + b) * INNER + tid] = f2bf(fmaxf(acc, 0.f));
    }
  } else {
    int j = tid - PROJ;
    for (int b = 0; b < BATCH; ++b)
      x_bf[((size_t)t * BATCH + b) * INNER + tid] = f2bf(emb[ai[b] * AD + j]);
  }
}

// ---------------- helpers ----------------
static __device__ __forceinline__ short8 bfrag_load(const float* __restrict__ w, int stride, int row, int k0) {
  const float* p = w + (size_t)row * stride + k0;
  f32x4 a = *reinterpret_cast<const f32x4*>(p);
  f32x4 b = *reinterpret_cast<const f32x4*>(p + 4);
  short8 r;
  r[0] = (short)f2bf(a[0]); r[1] = (short)f2bf(a[1]); r[2] = (short)f2bf(a[2]); r[3] = (short)f2bf(a[3]);
  r[4] = (short)f2bf(b[0]); r[5] = (short)f2bf(b[1]); r[6] = (short)f2bf(b[2]); r[7] = (short)f2bf(b[3]);
  return r;
}

struct Frag64 { i32x4 c[4]; };   // this lane's A-fragments for 4 k-chunks (4 x 16B)
union FU { i32x4 i; short8 s; };

static __device__ __forceinline__ bool fragok(const Frag64& f) {
  bool ok = true;
#pragma unroll
  for (int kk = 0; kk < 4; ++kk)
#pragma unroll
    for (int j = 0; j < 4; ++j)
      ok = ok & ((unsigned)f.c[kk][j] != SENTW);
  return ok;
}

// local read: bypass L1 (sc0), served by this XCD's L2; chunk stride 1024B (2 block regions)
static __device__ __forceinline__ void ld64_sc0(const unsigned int* p, Frag64& f) {
  asm volatile(
      "global_load_dwordx4 %0, %4, off sc0\n\t"
      "global_load_dwordx4 %1, %4, off offset:1024 sc0\n\t"
      "global_load_dwordx4 %2, %4, off offset:2048 sc0\n\t"
      "global_load_dwordx4 %3, %4, off offset:3072 sc0\n\t"
      "s_waitcnt vmcnt(0)"
      : "=&v"(f.c[0]), "=&v"(f.c[1]), "=&v"(f.c[2]), "=&v"(f.c[3])
      : "v"(p) : "memory");
}

// agent (MALL-coherent) read via compiler-proven atomics
static __device__ __forceinline__ void ld64_agent(const unsigned int* p, Frag64& f) {
  const unsigned long long* q = reinterpret_cast<const unsigned long long*>(p);
#pragma unroll
  for (int kk = 0; kk < 4; ++kk) {
    union { unsigned long long u[2]; i32x4 v; } t;
    t.u[0] = __hip_atomic_load(q + kk * 128,     __ATOMIC_RELAXED, __HIP_MEMORY_SCOPE_AGENT);
    t.u[1] = __hip_atomic_load(q + kk * 128 + 1, __ATOMIC_RELAXED, __HIP_MEMORY_SCOPE_AGENT);
    f.c[kk] = t.v;
  }
}

static __device__ __forceinline__ Frag64 poll_agent(const unsigned int* sp) {
  Frag64 f;
  int miss = 0;
  while (true) {
    ld64_agent(sp, f);
    if (__all((int)fragok(f))) break;
    if (++miss > 2) __builtin_amdgcn_s_sleep(1);
  }
  return f;
}

// poll local L2 copy (backoff); timeout -> permanent agent fallback (per call-site)
static __device__ __forceinline__ Frag64 poll_local(const unsigned int* lp, const unsigned int* sp, bool& shadow) {
  Frag64 f;
  if (!shadow) {
    int it = 0;
    while (true) {
      ld64_sc0(lp, f);
      if (__all((int)fragok(f))) return f;
      __builtin_amdgcn_s_sleep(1);
      if (++it > LOC_TO) { shadow = true; break; }
    }
  }
  return poll_agent(sp);
}

static __device__ __forceinline__ void mfma4(const Frag64& f, const short8* wf, f32x4* acc) {
#pragma unroll
  for (int kk = 0; kk < 4; ++kk) {
    FU u; u.i = f.c[kk];
#pragma unroll
    for (int g = 0; g < 4; ++g)
      acc[g] = __builtin_amdgcn_mfma_f32_16x16x32_bf16(u.s, wf[g * 4 + kk], acc[g], 0, 0, 0);
  }
}

static __device__ __forceinline__ void st_agent(unsigned int* p, unsigned int v) {
  __hip_atomic_store(p, v, __ATOMIC_RELAXED, __HIP_MEMORY_SCOPE_AGENT);
}
// consumer-side sentinel resets of the exact words this lane consumes
static __device__ __forceinline__ void reset_local(unsigned int* p) {
  const i32x4 s4 = {(int)SENTW, (int)SENTW, (int)SENTW, (int)SENTW};
#pragma unroll
  for (int kk = 0; kk < 4; ++kk)
    *reinterpret_cast<i32x4*>(p + kk * 256) = s4;
}
static __device__ __forceinline__ void reset_agent(unsigned int* p) {
  unsigned long long* q = reinterpret_cast<unsigned long long*>(p);
#pragma unroll
  for (int kk = 0; kk < 4; ++kk) {
    __hip_atomic_store(q + kk * 128,     0x7F7F7F7F7F7F7F7FULL, __ATOMIC_RELAXED, __HIP_MEMORY_SCOPE_AGENT);
    __hip_atomic_store(q + kk * 128 + 1, 0x7F7F7F7F7F7F7F7FULL, __ATOMIC_RELAXED, __HIP_MEMORY_SCOPE_AGENT);
  }
}

static __device__ __forceinline__ size_t slotw(int bg, int d) { return ((size_t)(bg * DEP + d)) * SLOTW; }

// ---------------- persistent 2-layer LSTM ----------------
// Roles self-assigned by PHYSICAL XCD (HW_REG_XCC_ID): XCD 0-3 = layer0 bg 0-3,
// XCD 4-7 = layer1 bg 0-3; blk = slot within XCD owns hid [blk*16,+16).
// Self-recurrence: plain stores -> own XCD L2, sc0 sentinel data-poll (+agent fallback).
// Cross-layer h0 and throttle flags: agent atomics (MALL), pipelined off the chain.
// Ring discipline: consumer lane resets its own words 8-9 steps behind; L1->L0 flag
// throttle (every 4 steps, tgt t-4) orders resets before producer lap-reuse.
template<int L>
static __device__ void lstm_body(
    const unsigned short* __restrict__ x_bf,
    const float* __restrict__ wih, const float* __restrict__ whh,
    const float* __restrict__ bih, const float* __restrict__ bhh,
    unsigned int* __restrict__ h0l, unsigned int* __restrict__ h0r,
    unsigned int* __restrict__ h1l, unsigned int* __restrict__ h1r,
    float* __restrict__ h1fin, unsigned int* __restrict__ flags,
    int bg, int blk, float* __restrict__ spart)
{
  constexpr int KI = (L == 0) ? 2 : 4;

  const int tid  = threadIdx.x;
  const int lane = tid & 63;
  const int wv   = tid >> 6;
  const int q    = lane >> 4;
  const int ln   = lane & 15;
  const int hid0 = blk << 4;
  const int m    = tid >> 4;
  const int n    = tid & 15;
  const int cbase = (wv * 8 + (q >> 1)) * 128 + ln * 8 + (q & 1) * 4;

  float bias[4];
#pragma unroll
  for (int g = 0; g < 4; ++g)
    bias[g] = bih[g * HID + hid0 + n] + bhh[g * HID + hid0 + n];

  short8 fih[4 * KI];
#pragma unroll
  for (int g = 0; g < 4; ++g)
#pragma unroll
    for (int kk = 0; kk < KI; ++kk)
      fih[g * KI + kk] = bfrag_load(wih, (L == 0) ? INNER : HID,
                                    g * HID + hid0 + ln, (wv * KI + kk) * 32 + q * 8);
  short8 fhh[16];
#pragma unroll
  for (int g = 0; g < 4; ++g)
#pragma unroll
    for (int kk = 0; kk < 4; ++kk)
      fhh[g * 4 + kk] = bfrag_load(whh, HID, g * HID + hid0 + ln, (wv * 4 + kk) * 32 + q * 8);

  const int wo = blk * 128 + m * 8 + (n >> 1);  // producer word (n even stores the pair)
  float c_state = 0.f;
  bool sh = false;

  for (int t = 0; t < T_STEPS; ++t) {
    f32x4 acc[4];
#pragma unroll
    for (int g = 0; g < 4; ++g) acc[g] = (f32x4){0.f, 0.f, 0.f, 0.f};

    if constexpr (L == 0) {
      // x-side first (static, cached)
      const unsigned short* xr = x_bf + ((size_t)t * BATCH + bg * 16 + ln) * INNER + q * 8;
#pragma unroll
      for (int kk = 0; kk < KI; ++kk) {
        short8 xa = *reinterpret_cast<const short8*>(xr + (wv * KI + kk) * 32);
#pragma unroll
        for (int g = 0; g < 4; ++g)
          acc[g] = __builtin_amdgcn_mfma_f32_16x16x32_bf16(xa, fih[g * KI + kk], acc[g], 0, 0, 0);
      }
      // ring-reuse throttle vs layer 1
      if ((t & 3) == 0 && t >= 8) {
        const unsigned int* fp = flags + (bg * 32 + (lane & 31)) * 32;
        unsigned int tgt = (unsigned)(t - 4);
        while (true) {
          unsigned int v = __hip_atomic_load(fp, __ATOMIC_RELAXED, __HIP_MEMORY_SCOPE_AGENT);
          if (__all((int)(v >= tgt))) break;
          __builtin_amdgcn_s_sleep(1);
        }
        asm volatile("" ::: "memory");
      }
      if (t > 0) {  // self-recurrence: local XCD-L2 data-poll
        size_t s = slotw(bg, (t - 1) & (DEP - 1)) + cbase;
        Frag64 f = poll_local(h0l + s, h0r + s, sh);
        mfma4(f, fhh, acc);
        if (t >= 9) reset_local(h0l + slotw(bg, (t - 9) & (DEP - 1)) + cbase);
      }
    } else {
      if (t > 0) {  // self-recurrence: local
        size_t s = slotw(bg, (t - 1) & (DEP - 1)) + cbase;
        Frag64 f = poll_local(h1l + s, h1r + s, sh);
        mfma4(f, fhh, acc);
        if (t >= 9) {
          size_t r = slotw(bg, (t - 9) & (DEP - 1)) + cbase;
          reset_local(h1l + r);
          reset_agent(h1r + r);
        }
      }
      {  // input: h0[t] from layer 0 (cross-XCD via MALL, pipelined)
        size_t s = slotw(bg, t & (DEP - 1)) + cbase;
        Frag64 f = poll_agent(h0r + s);
        mfma4(f, fih, acc);
        if (t >= 8) reset_agent(h0r + slotw(bg, (t - 8) & (DEP - 1)) + cbase);
      }
    }

    // K-split partial exchange (XOR swizzle, conflict-free; double-buffered)
    float* sp_w = spart + (t & 1) * 4096;
#pragma unroll
    for (int g = 0; g < 4; ++g)
#pragma unroll
      for (int r = 0; r < 4; ++r)
        sp_w[(((wv * 4 + g) * 4 + r) * 4 + (q ^ r)) * 16 + ln] = acc[g][r];
    __syncthreads();

    if constexpr (L == 1) {  // publish progress (syncthreads drained resets + reads)
      if ((t & 3) == 3 && tid == 0)
        st_agent(flags + (bg * 32 + blk) * 32, (unsigned)(t + 1));
    }

    float gate[4];
#pragma unroll
    for (int g = 0; g < 4; ++g) {
      float s = bias[g];
#pragma unroll
      for (int w2 = 0; w2 < 4; ++w2)
        s += sp_w[(((w2 * 4 + g) * 4 + (m & 3)) * 4 + ((m >> 2) ^ (m & 3))) * 16 + n];
      gate[g] = s;
    }
    float gi = sigmoidf_(gate[0]);
    float gf = sigmoidf_(gate[1]);
    float gc = tanhf_(gate[2]);
    float go = sigmoidf_(gate[3]);
    c_state = gf * c_state + gi * gc;
    float h = go * tanhf_(c_state);

    // publish h: pack (n even | n+1); block-major -> full-line coalesced stores
    float hp = __shfl_xor(h, 1);
    unsigned int wword = (unsigned)f2bf(h) | ((unsigned)f2bf(hp) << 16);
    if constexpr (L == 0) {
      if (!(n & 1)) {
        size_t s_cur = slotw(bg, t & (DEP - 1)) + wo;
        h0l[s_cur] = wword;              // local L2 for own group
        st_agent(h0r + s_cur, wword);    // MALL for layer 1
      }
    } else {
      if (!(n & 1)) {
        size_t s_cur = slotw(bg, t & (DEP - 1)) + wo;
        h1l[s_cur] = wword;
        st_agent(h1r + s_cur, wword);    // fallback shadow
      }
      if (t == T_STEPS - 1)
        h1fin[(size_t)(bg * 16 + m) * HID + hid0 + n] = h;
    }
  }
}

__global__ __launch_bounds__(256, 1) void k_lstm(
    const unsigned short* __restrict__ x_bf,
    const float* __restrict__ w_ih0, const float* __restrict__ w_hh0,
    const float* __restrict__ b_ih0, const float* __restrict__ b_hh0,
    const float* __restrict__ w_ih1, const float* __restrict__ w_hh1,
    const float* __restrict__ b_ih1, const float* __restrict__ b_hh1,
    unsigned int* h0l, unsigned int* h0r, unsigned int* h1l, unsigned int* h1r,
    float* h1fin, unsigned int* flags, unsigned int* ctrl)
{
  __shared__ float spart[2 * 4096];
  __shared__ int s_role;
  if (threadIdx.x == 0) {
    unsigned int xcc;
    asm volatile("s_getreg_b32 %0, hwreg(HW_REG_XCC_ID)" : "=s"(xcc));
    xcc &= 7u;
    unsigned int slot = __hip_atomic_fetch_add(&ctrl[xcc], 1u, __ATOMIC_ACQ_REL, __HIP_MEMORY_SCOPE_AGENT);
    __hip_atomic_fetch_add(&ctrl[8], 1u, __ATOMIC_ACQ_REL, __HIP_MEMORY_SCOPE_AGENT);
    while (__hip_atomic_load(&ctrl[8], __ATOMIC_ACQUIRE, __HIP_MEMORY_SCOPE_AGENT) < 256u)
      __builtin_amdgcn_s_sleep(2);
    int role;
    if (slot < 32u) {
      role = (int)(xcc * 32u + slot);
    } else {
      unsigned int c[8];
      for (int j = 0; j < 8; ++j)
        c[j] = __hip_atomic_load(&ctrl[j], __ATOMIC_RELAXED, __HIP_MEMORY_SCOPE_AGENT);
      int k = (int)slot - 32;
      for (unsigned int x = 0; x < xcc; ++x) k += (c[x] > 32u) ? (int)(c[x] - 32u) : 0;
      role = -1;
      for (int j = 0; j < 8; ++j) {
        int d = (c[j] < 32u) ? (int)(32u - c[j]) : 0;
        if (role < 0) { if (k < d) role = j * 32 + (int)c[j] + k; else k -= d; }
      }
    }
    s_role = role;
  }
  __syncthreads();
  const int role = s_role;
  const int gid  = role >> 5;       // == physical XCD for primary roles
  const int blk  = role & 31;
  const int bg   = gid & 3;
  if (gid < 4)
    lstm_body<0>(x_bf, w_ih0, w_hh0, b_ih0, b_hh0, h0l, h0r, h1l, h1r, h1fin, flags, bg, blk, spart);
  else
    lstm_body<1>(x_bf, w_ih1, w_hh1, b_ih1, b_hh1, h0l, h0r, h1l, h1r, h1fin, flags, bg, blk, spart);
}

// ---------------- output head on final h1 (fp32) ----------------
__global__ __launch_bounds__(256) void k_head(
    const float* __restrict__ h1, const float* __restrict__ w1, const float* __restrict__ b1,
    const float* __restrict__ w2, const float* __restrict__ b2, float* __restrict__ out)
{
  int b = blockIdx.x, tid = threadIdx.x;
  __shared__ float sh[HID];
  __shared__ float sm[2 * HID];
  for (int k = tid; k < HID; k += 256) sh[k] = h1[(size_t)b * HID + k];
  __syncthreads();
#pragma unroll
  for (int r0 = 0; r0 < 4; ++r0) {
    int row = r0 * 256 + tid;
    const f32x4* wr = reinterpret_cast<const f32x4*>(w1 + (size_t)row * HID);
    float s = 0.f;
#pragma unroll 4
    for (int k = 0; k < HID / 4; ++k) {
      f32x4 v = wr[k];
      s += v[0] * sh[k * 4] + v[1] * sh[k * 4 + 1] + v[2] * sh[k * 4 + 2] + v[3] * sh[k * 4 + 3];
    }
    sm[row] = fmaxf(b1[row] + s, 0.f);
  }
  __syncthreads();
  if (tid < 32) {
    const f32x4* wr = reinterpret_cast<const f32x4*>(w2 + (size_t)tid * 2 * HID);
    float s = b2[tid];
#pragma unroll 4
    for (int k = 0; k < 2 * HID / 4; ++k) {
      f32x4 v = wr[k];
      s += v[0] * sm[k * 4] + v[1] * sm[k * 4 + 1] + v[2] * sm[k * 4 + 2] + v[3] * sm[k * 4 + 3];
    }
    if (tid >= 24) s = sigmoidf_(s);   // CAT_FLAGS[24:]
    out[b * 32 + tid] = s;
  }
}

extern "C" void kernel_launch(void* const* d_in, const int* in_sizes, int n_in,
                              void* d_out, int out_size, void* d_ws, size_t ws_size,
                              hipStream_t stream) {
  const float* ws_in  = (const float*)d_in[0];
  const int*   aidx   = (const int*)d_in[1];
  const float* emb    = (const float*)d_in[2];
  const float* in_w   = (const float*)d_in[3];
  const float* in_b   = (const float*)d_in[4];
  const float* w_ih0  = (const float*)d_in[5];
  const float* w_hh0  = (const float*)d_in[6];
  const float* b_ih0  = (const float*)d_in[7];
  const float* b_hh0  = (const float*)d_in[8];
  const float* w_ih1  = (const float*)d_in[9];
  const float* w_hh1  = (const float*)d_in[10];
  const float* b_ih1  = (const float*)d_in[11];
  const float* b_hh1  = (const float*)d_in[12];
  const float* out_w1 = (const float*)d_in[13];
  const float* out_b1 = (const float*)d_in[14];
  const float* out_w2 = (const float*)d_in[15];
  const float* out_b2 = (const float*)d_in[16];

  unsigned char* ws = (unsigned char*)d_ws;
  const size_t X_OFF   = 0;                         // 16,777,216
  const size_t RING_SZ = 4u * DEP * SLOTW * 4;      // 1,048,576 per ring
  const size_t H0L_OFF = 16777216;
  const size_t H0R_OFF = H0L_OFF + RING_SZ;
  const size_t H1L_OFF = H0R_OFF + RING_SZ;
  const size_t H1R_OFF = H1L_OFF + RING_SZ;
  const size_t HF_OFF  = H1R_OFF + RING_SZ;         // h1fin 131,072
  const size_t FL_OFF  = HF_OFF + 131072;           // flags 16,384
  const size_t CT_OFF  = FL_OFF + 16384;            // ctrl 256
  unsigned short* x_bf  = (unsigned short*)(ws + X_OFF);
  unsigned int*   h0l   = (unsigned int*)(ws + H0L_OFF);
  unsigned int*   h0r   = (unsigned int*)(ws + H0R_OFF);
  unsigned int*   h1l   = (unsigned int*)(ws + H1L_OFF);
  unsigned int*   h1r   = (unsigned int*)(ws + H1R_OFF);
  float*          h1fin = (float*)(ws + HF_OFF);
  unsigned int*   flags = (unsigned int*)(ws + FL_OFF);
  unsigned int*   ctrl  = (unsigned int*)(ws + CT_OFF);

  hipMemsetAsync(ws + H0L_OFF, 0x7F, 4 * RING_SZ, stream);   // rings -> sentinel
  hipMemsetAsync(ws + FL_OFF, 0, 16384 + 256, stream);       // flags + ctrl -> 0
  k_prep<<<dim3(T_STEPS), dim3(256), 0, stream>>>(ws_in, aidx, emb, in_w, in_b, x_bf);
  k_lstm<<<dim3(256), dim3(256), 0, stream>>>(x_bf, w_ih0, w_hh0, b_ih0, b_hh0,
                                              w_ih1, w_hh1, b_ih1, b_hh1,
                                              h0l, h0r, h1l, h1r, h1fin, flags, ctrl);
  k_head<<<dim3(BATCH), dim3(256), 0, stream>>>(h1fin, out_w1, out_b1, out_w2, out_b2, (float*)d_out);
}

// Round 7
// 1493.643 us; speedup vs baseline: 36.1240x; 36.1240x over previous
//
#include <hip/hip_runtime.h>

#define T_STEPS 512
#define BATCH   64
#define IN_SZ   32
#define AD      32
#define INNER   256
#define PROJ    224
#define HID     512
#define SENTW   0x7F7F7F7Fu   // bf16 0x7F7F = 3.3e38; impossible for |h|<1 outputs
#define DEP     16            // ring depth (slots per batch-group)
#define RST     6             // producer reset distance (slots ahead)
#define SLOTW   4096          // u32 words per 16KB slot

typedef __attribute__((ext_vector_type(8))) short short8;
typedef __attribute__((ext_vector_type(4))) float f32x4;
typedef __attribute__((ext_vector_type(4))) int   i32x4;

static __device__ __forceinline__ unsigned short f2bf(float f) {
  unsigned int u = __float_as_uint(f);
  u += 0x7FFFu + ((u >> 16) & 1u);
  return (unsigned short)(u >> 16);
}
static __device__ __forceinline__ float sigmoidf_(float x) { return 1.f / (1.f + __expf(-x)); }
static __device__ __forceinline__ float tanhf_(float x) {
  float e = __expf(-2.f * fabsf(x));
  float r = (1.f - e) / (1.f + e);
  return x < 0.f ? -r : r;
}

// ---------------- kernel A: x = [relu(in_w@state+in_b) | emb[idx]] bf16, [t][b][256]
__global__ __launch_bounds__(256) void k_prep(
    const float* __restrict__ ws_in, const int* __restrict__ act_idx,
    const float* __restrict__ emb, const float* __restrict__ in_w,
    const float* __restrict__ in_b, unsigned short* __restrict__ x_bf)
{
  int t = blockIdx.x;
  int tid = threadIdx.x;
  __shared__ float st[BATCH * IN_SZ];
  __shared__ int ai[BATCH];
  for (int i = tid; i < BATCH * IN_SZ; i += 256) {
    int b = i >> 5, k = i & 31;
    st[i] = ws_in[((size_t)b * T_STEPS + t) * IN_SZ + k];
  }
  if (tid < BATCH) ai[tid] = act_idx[tid * T_STEPS + t];
  __syncthreads();
  if (tid < PROJ) {
    float w[IN_SZ];
    const float* wrow = in_w + tid * IN_SZ;
#pragma unroll
    for (int k = 0; k < IN_SZ; ++k) w[k] = wrow[k];
    float bb = in_b[tid];
    for (int b = 0; b < BATCH; ++b) {
      float acc = bb;
      const float* sb = st + b * IN_SZ;
#pragma unroll
      for (int k = 0; k < IN_SZ; ++k) acc += w[k] * sb[k];
      x_bf[((size_t)t * BATCH + b) * INNER + tid] = f2bf(fmaxf(acc, 0.f));
    }
  } else {
    int j = tid - PROJ;
    for (int b = 0; b < BATCH; ++b)
      x_bf[((size_t)t * BATCH + b) * INNER + tid] = f2bf(emb[ai[b] * AD + j]);
  }
}

// ---------------- helpers ----------------
static __device__ __forceinline__ short8 bfrag_load(const float* __restrict__ w, int stride, int row, int k0) {
  const float* p = w + (size_t)row * stride + k0;
  f32x4 a = *reinterpret_cast<const f32x4*>(p);
  f32x4 b = *reinterpret_cast<const f32x4*>(p + 4);
  short8 r;
  r[0] = (short)f2bf(a[0]); r[1] = (short)f2bf(a[1]); r[2] = (short)f2bf(a[2]); r[3] = (short)f2bf(a[3]);
  r[4] = (short)f2bf(b[0]); r[5] = (short)f2bf(b[1]); r[6] = (short)f2bf(b[2]); r[7] = (short)f2bf(b[3]);
  return r;
}

struct Frag64 { unsigned long long u[8]; };   // this lane's 4 k-chunks x 16B
union FU2 { unsigned long long u[2]; short8 s; };

// load this lane's 64B (4 chunks at 1KB stride) via agent-scope relaxed atomics
static __device__ __forceinline__ void ld64(const unsigned long long* q, Frag64& f) {
#pragma unroll
  for (int kk = 0; kk < 4; ++kk) {
    f.u[kk * 2]     = __hip_atomic_load(q + kk * 128,     __ATOMIC_RELAXED, __HIP_MEMORY_SCOPE_AGENT);
    f.u[kk * 2 + 1] = __hip_atomic_load(q + kk * 128 + 1, __ATOMIC_RELAXED, __HIP_MEMORY_SCOPE_AGENT);
  }
}
static __device__ __forceinline__ bool fragok(const Frag64& f) {
  bool ok = true;
#pragma unroll
  for (int i = 0; i < 8; ++i)
    ok = ok & ((unsigned)(f.u[i] >> 32) != SENTW) & ((unsigned)f.u[i] != SENTW);
  return ok;
}

static __device__ __forceinline__ Frag64 poll_one(const unsigned long long* q) {
  Frag64 f;
  int miss = 0;
  while (true) {
    ld64(q, f);
    if (__all((int)fragok(f))) break;
    if (++miss > 2) __builtin_amdgcn_s_sleep(1);
  }
  return f;
}
// joint poll of two rings: single detect latency for whichever arrives last
static __device__ __forceinline__ void poll_two(const unsigned long long* qa, const unsigned long long* qb,
                                                Frag64& fa, Frag64& fb) {
  int miss = 0;
  while (true) {
    ld64(qa, fa);
    ld64(qb, fb);
    if (__all((int)(fragok(fa) & fragok(fb)))) break;
    if (++miss > 2) __builtin_amdgcn_s_sleep(1);
  }
}

static __device__ __forceinline__ void mfma4(const Frag64& f, const short8* wf, f32x4* acc) {
#pragma unroll
  for (int kk = 0; kk < 4; ++kk) {
    FU2 u; u.u[0] = f.u[kk * 2]; u.u[1] = f.u[kk * 2 + 1];
#pragma unroll
    for (int g = 0; g < 4; ++g)
      acc[g] = __builtin_amdgcn_mfma_f32_16x16x32_bf16(u.s, wf[g * 4 + kk], acc[g], 0, 0, 0);
  }
}

static __device__ __forceinline__ void st_agent(unsigned int* p, unsigned int v) {
  __hip_atomic_store(p, v, __ATOMIC_RELAXED, __HIP_MEMORY_SCOPE_AGENT);
}

static __device__ __forceinline__ size_t slotw(int bg, int d) { return ((size_t)(bg * DEP + d)) * SLOTW; }

// ---------------- persistent 2-layer LSTM ----------------
// 256 blocks; xg=blockIdx&7: layer=xg>=4, bg=xg&3; blk=blockIdx>>3 owns hid [blk*16,+16).
// ALL cross-block traffic agent-scope (MALL-coherent). Data-as-flag sentinel rings
// (depth 16); PRODUCER-side resets at +6 (1x amplification); zero drains in the loop.
// L1: joint poll of h1[t-1] + h0[t] (one RTT). L1 publishes consumption flags every
// 2 steps; L0 guards ring reuse every 4 steps (tgt t-4) => lag <= 8 <= D-RST-1 = 9.
template<int L>
static __device__ void lstm_body(
    const unsigned short* __restrict__ x_bf,
    const float* __restrict__ wih, const float* __restrict__ whh,
    const float* __restrict__ bih, const float* __restrict__ bhh,
    unsigned int* __restrict__ h0w, unsigned int* __restrict__ h1w,
    float* __restrict__ h1fin, unsigned int* __restrict__ flags,
    int bg, int blk, float* __restrict__ spart)
{
  constexpr int KI = (L == 0) ? 2 : 4;

  const int tid  = threadIdx.x;
  const int lane = tid & 63;
  const int wv   = tid >> 6;
  const int q    = lane >> 4;
  const int ln   = lane & 15;
  const int hid0 = blk << 4;
  const int m    = tid >> 4;
  const int n    = tid & 15;
  // consumer u64 base: chunk kk at +kk*128 u64 (1KB); block-major slot layout
  const int cb64 = (wv * 8 + (q >> 1)) * 64 + ln * 4 + (q & 1) * 2;

  float bias[4];
#pragma unroll
  for (int g = 0; g < 4; ++g)
    bias[g] = bih[g * HID + hid0 + n] + bhh[g * HID + hid0 + n];

  short8 fih[4 * KI];
#pragma unroll
  for (int g = 0; g < 4; ++g)
#pragma unroll
    for (int kk = 0; kk < KI; ++kk)
      fih[g * KI + kk] = bfrag_load(wih, (L == 0) ? INNER : HID,
                                    g * HID + hid0 + ln, (wv * KI + kk) * 32 + q * 8);
  short8 fhh[16];
#pragma unroll
  for (int g = 0; g < 4; ++g)
#pragma unroll
    for (int kk = 0; kk < 4; ++kk)
      fhh[g * 4 + kk] = bfrag_load(whh, HID, g * HID + hid0 + ln, (wv * 4 + kk) * 32 + q * 8);

  const int wo = blk * 128 + m * 8 + (n >> 1);  // producer word (even n stores the pair)
  float c_state = 0.f;

  for (int t = 0; t < T_STEPS; ++t) {
    f32x4 acc[4];
#pragma unroll
    for (int g = 0; g < 4; ++g) acc[g] = (f32x4){0.f, 0.f, 0.f, 0.f};

    if constexpr (L == 0) {
      // x-side first (static, cached)
      const unsigned short* xr = x_bf + ((size_t)t * BATCH + bg * 16 + ln) * INNER + q * 8;
#pragma unroll
      for (int kk = 0; kk < KI; ++kk) {
        short8 xa = *reinterpret_cast<const short8*>(xr + (wv * KI + kk) * 32);
#pragma unroll
        for (int g = 0; g < 4; ++g)
          acc[g] = __builtin_amdgcn_mfma_f32_16x16x32_bf16(xa, fih[g * KI + kk], acc[g], 0, 0, 0);
      }
      // ring-reuse guard vs layer 1 (every 4 steps; lag bound 8 <= D-RST-1 = 9)
      if ((t & 3) == 0 && t >= 8) {
        const unsigned int* fp = flags + (bg * 32 + (lane & 31)) * 32;
        unsigned int tgt = (unsigned)(t - 4);
        while (true) {
          unsigned int v = __hip_atomic_load(fp, __ATOMIC_RELAXED, __HIP_MEMORY_SCOPE_AGENT);
          if (__all((int)(v >= tgt))) break;
          __builtin_amdgcn_s_sleep(1);
        }
        asm volatile("" ::: "memory");
      }
      if (t > 0) {  // self-recurrence: data-poll h0[t-1]
        Frag64 f = poll_one(reinterpret_cast<const unsigned long long*>(h0w + slotw(bg, (t - 1) & (DEP - 1))) + cb64);
        mfma4(f, fhh, acc);
      }
    } else {
      if (t > 0) {  // joint poll: h1[t-1] (self) + h0[t] (cross) in ONE detect loop
        Frag64 fa, fb;
        poll_two(reinterpret_cast<const unsigned long long*>(h1w + slotw(bg, (t - 1) & (DEP - 1))) + cb64,
                 reinterpret_cast<const unsigned long long*>(h0w + slotw(bg, t & (DEP - 1))) + cb64, fa, fb);
        mfma4(fa, fhh, acc);
        mfma4(fb, fih, acc);
      } else {
        Frag64 fb = poll_one(reinterpret_cast<const unsigned long long*>(h0w + slotw(bg, 0)) + cb64);
        mfma4(fb, fih, acc);
      }
    }

    // K-split partial exchange (XOR swizzle, conflict-free; double-buffered, 1 barrier)
    float* sp_w = spart + (t & 1) * 4096;
#pragma unroll
    for (int g = 0; g < 4; ++g)
#pragma unroll
      for (int r = 0; r < 4; ++r)
        sp_w[(((wv * 4 + g) * 4 + r) * 4 + (q ^ r)) * 16 + ln] = acc[g][r];
    __syncthreads();

    if constexpr (L == 1) {  // consumption flag (h0[t] loads complete before barrier)
      if ((t & 1) == 1 && tid == 0)
        st_agent(flags + (bg * 32 + blk) * 32, (unsigned)(t + 1));
    }

    float gate[4];
#pragma unroll
    for (int g = 0; g < 4; ++g) {
      float s = bias[g];
#pragma unroll
      for (int w2 = 0; w2 < 4; ++w2)
        s += sp_w[(((w2 * 4 + g) * 4 + (m & 3)) * 4 + ((m >> 2) ^ (m & 3))) * 16 + n];
      gate[g] = s;
    }
    float gi = sigmoidf_(gate[0]);
    float gf = sigmoidf_(gate[1]);
    float gc = tanhf_(gate[2]);
    float go = sigmoidf_(gate[3]);
    c_state = gf * c_state + gi * gc;
    float h = go * tanhf_(c_state);

    // publish h (pack even|odd pair) + producer-side reset of slot t+RST
    float hp = __shfl_xor(h, 1);
    unsigned int wword = (unsigned)f2bf(h) | ((unsigned)f2bf(hp) << 16);
    if constexpr (L == 0) {
      if (!(n & 1)) {
        st_agent(h0w + slotw(bg, t & (DEP - 1)) + wo, wword);
        st_agent(h0w + slotw(bg, (t + RST) & (DEP - 1)) + wo, SENTW);
      }
    } else {
      if (!(n & 1)) {
        st_agent(h1w + slotw(bg, t & (DEP - 1)) + wo, wword);
        st_agent(h1w + slotw(bg, (t + RST) & (DEP - 1)) + wo, SENTW);
      }
      if (t == T_STEPS - 1)
        h1fin[(size_t)(bg * 16 + m) * HID + hid0 + n] = h;
    }
  }
}

__global__ __launch_bounds__(256, 1) void k_lstm(
    const unsigned short* __restrict__ x_bf,
    const float* __restrict__ w_ih0, const float* __restrict__ w_hh0,
    const float* __restrict__ b_ih0, const float* __restrict__ b_hh0,
    const float* __restrict__ w_ih1, const float* __restrict__ w_hh1,
    const float* __restrict__ b_ih1, const float* __restrict__ b_hh1,
    unsigned int* h0w, unsigned int* h1w, float* h1fin, unsigned int* flags)
{
  __shared__ float spart[2 * 4096];
  const int xg  = blockIdx.x & 7;
  const int blk = blockIdx.x >> 3;
  const int bg  = xg & 3;
  if (xg < 4)
    lstm_body<0>(x_bf, w_ih0, w_hh0, b_ih0, b_hh0, h0w, h1w, h1fin, flags, bg, blk, spart);
  else
    lstm_body<1>(x_bf, w_ih1, w_hh1, b_ih1, b_hh1, h0w, h1w, h1fin, flags, bg, blk, spart);
}

// ---------------- output head on final h1 (fp32) ----------------
__global__ __launch_bounds__(256) void k_head(
    const float* __restrict__ h1, const float* __restrict__ w1, const float* __restrict__ b1,
    const float* __restrict__ w2, const float* __restrict__ b2, float* __restrict__ out)
{
  int b = blockIdx.x, tid = threadIdx.x;
  __shared__ float sh[HID];
  __shared__ float sm[2 * HID];
  for (int k = tid; k < HID; k += 256) sh[k] = h1[(size_t)b * HID + k];
  __syncthreads();
#pragma unroll
  for (int r0 = 0; r0 < 4; ++r0) {
    int row = r0 * 256 + tid;
    const f32x4* wr = reinterpret_cast<const f32x4*>(w1 + (size_t)row * HID);
    float s = 0.f;
#pragma unroll 4
    for (int k = 0; k < HID / 4; ++k) {
      f32x4 v = wr[k];
      s += v[0] * sh[k * 4] + v[1] * sh[k * 4 + 1] + v[2] * sh[k * 4 + 2] + v[3] * sh[k * 4 + 3];
    }
    sm[row] = fmaxf(b1[row] + s, 0.f);
  }
  __syncthreads();
  if (tid < 32) {
    const f32x4* wr = reinterpret_cast<const f32x4*>(w2 + (size_t)tid * 2 * HID);
    float s = b2[tid];
#pragma unroll 4
    for (int k = 0; k < 2 * HID / 4; ++k) {
      f32x4 v = wr[k];
      s += v[0] * sm[k * 4] + v[1] * sm[k * 4 + 1] + v[2] * sm[k * 4 + 2] + v[3] * sm[k * 4 + 3];
    }
    if (tid >= 24) s = sigmoidf_(s);   // CAT_FLAGS[24:]
    out[b * 32 + tid] = s;
  }
}

extern "C" void kernel_launch(void* const* d_in, const int* in_sizes, int n_in,
                              void* d_out, int out_size, void* d_ws, size_t ws_size,
                              hipStream_t stream) {
  const float* ws_in  = (const float*)d_in[0];
  const int*   aidx   = (const int*)d_in[1];
  const float* emb    = (const float*)d_in[2];
  const float* in_w   = (const float*)d_in[3];
  const float* in_b   = (const float*)d_in[4];
  const float* w_ih0  = (const float*)d_in[5];
  const float* w_hh0  = (const float*)d_in[6];
  const float* b_ih0  = (const float*)d_in[7];
  const float* b_hh0  = (const float*)d_in[8];
  const float* w_ih1  = (const float*)d_in[9];
  const float* w_hh1  = (const float*)d_in[10];
  const float* b_ih1  = (const float*)d_in[11];
  const float* b_hh1  = (const float*)d_in[12];
  const float* out_w1 = (const float*)d_in[13];
  const float* out_b1 = (const float*)d_in[14];
  const float* out_w2 = (const float*)d_in[15];
  const float* out_b2 = (const float*)d_in[16];

  unsigned char* ws = (unsigned char*)d_ws;
  const size_t X_OFF   = 0;                        // 16,777,216
  const size_t RING_SZ = 4u * DEP * SLOTW * 4;     // 1,048,576 per ring
  const size_t H0_OFF  = 16777216;
  const size_t H1_OFF  = H0_OFF + RING_SZ;
  const size_t HF_OFF  = H1_OFF + RING_SZ;         // h1fin 131,072
  const size_t FL_OFF  = HF_OFF + 131072;          // flags 16,384
  unsigned short* x_bf  = (unsigned short*)(ws + X_OFF);
  unsigned int*   h0w   = (unsigned int*)(ws + H0_OFF);
  unsigned int*   h1w   = (unsigned int*)(ws + H1_OFF);
  float*          h1fin = (float*)(ws + HF_OFF);
  unsigned int*   flags = (unsigned int*)(ws + FL_OFF);

  hipMemsetAsync(ws + H0_OFF, 0x7F, 2 * RING_SZ, stream);  // rings -> sentinel
  hipMemsetAsync(ws + FL_OFF, 0, 16384, stream);
  k_prep<<<dim3(T_STEPS), dim3(256), 0, stream>>>(ws_in, aidx, emb, in_w, in_b, x_bf);
  k_lstm<<<dim3(256), dim3(256), 0, stream>>>(x_bf, w_ih0, w_hh0, b_ih0, b_hh0,
                                              w_ih1, w_hh1, b_ih1, b_hh1,
                                              h0w, h1w, h1fin, flags);
  k_head<<<dim3(BATCH), dim3(256), 0, stream>>>(h1fin, out_w1, out_b1, out_w2, out_b2, (float*)d_out);
}